// Round 7
// baseline (125.524 us; speedup 1.0000x reference)
//
#include <hip/hip_runtime.h>
#include <math.h>

typedef unsigned short ushortT;
typedef __attribute__((ext_vector_type(8))) short bf16x8;
typedef __attribute__((ext_vector_type(8))) unsigned short u16x8;
typedef __attribute__((ext_vector_type(4))) float f32x4;
typedef float f32x4u __attribute__((ext_vector_type(4), aligned(4)));

#define NN   512
#define UU   2048
#define VV   43
#define HH   512
#define KMIX 10
#define NCLS 512
#define EPSF 1e-5f
#define KCAT 555     // H + V

// d_out offsets (floats)
#define OFF_DIST  0
#define OFF_H2    262144
#define OFF_H3    524288
#define OFF_PHI   786432
#define OFF_WT    1835008
#define OFF_KAPPA 1857024

__device__ __forceinline__ ushortT f2bf(float f) {
    unsigned int u = __builtin_bit_cast(unsigned int, f);
    u = (u + 0x7fffu + ((u >> 16) & 1u)) >> 16;
    return (ushortT)u;
}

// ---------------------------------------------------------------------------
// Merged attn (blocks 0..511) + pack (blocks 512..2095, x8 vectorized).
__global__ __launch_bounds__(256) void attn_pack(
    const float* __restrict__ xt, const float* __restrict__ cx,
    const float* __restrict__ eh, const float* __restrict__ wt_1,
    const float* __restrict__ Ww, const float* __restrict__ Wb,
    const float* __restrict__ kappa_prev,
    float* __restrict__ phi_out, float* __restrict__ wt_out,
    float* __restrict__ kappa_out, ushortT* __restrict__ A2,
    const float* __restrict__ w2ih, const float* __restrict__ w2hh,
    const float* __restrict__ w3ih, const float* __restrict__ w3hh,
    const float* __restrict__ Yw, const float* __restrict__ h2p,
    const float* __restrict__ h3p,
    ushortT* __restrict__ W2i, ushortT* __restrict__ W2h,
    ushortT* __restrict__ W3i, ushortT* __restrict__ W3h,
    ushortT* __restrict__ Ywb, ushortT* __restrict__ A2h, ushortT* __restrict__ A3h)
{
    __shared__ float x[KCAT];
    __shared__ float sm[32];
    __shared__ float aL[KMIX], bL[KMIX], kL[KMIX], um[KMIX];
    __shared__ float red[4*VV];
    __shared__ float wtv[VV+1];

    int bb = blockIdx.x, t = threadIdx.x;

    if (bb >= NN) {
        // ---------------- pack path: 8 elems per thread ----------------
        int unit = (bb - NN)*256 + t;
        int e = unit*8;
        auto cvt8 = [&](const float* src, ushortT* dst, int off) {
            float4 f0 = *(const float4*)(src + off);
            float4 f1 = *(const float4*)(src + off + 4);
            u16x8 o;
            o[0]=f2bf(f0.x); o[1]=f2bf(f0.y); o[2]=f2bf(f0.z); o[3]=f2bf(f0.w);
            o[4]=f2bf(f1.x); o[5]=f2bf(f1.y); o[6]=f2bf(f1.z); o[7]=f2bf(f1.w);
            *(u16x8*)(dst + off) = o;
        };
        if (e < 98304) {               // W2i: 1536 x 64, cols >=44 zero-padded
            int r = e >> 6, c = e & 63;
            u16x8 o;
#pragma unroll
            for (int i = 0; i < 8; ++i) {
                int cc = c + i;
                o[i] = f2bf(cc < 44 ? w2ih[r*44 + cc] : 0.f);
            }
            *(u16x8*)(W2i + e) = o;
            return;
        }
        e -= 98304;
        if (e < 786432) { cvt8(w2hh, W2h, e); return; }
        e -= 786432;
        if (e < 786432) { cvt8(w3ih, W3i, e); return; }
        e -= 786432;
        if (e < 786432) { cvt8(w3hh, W3h, e); return; }
        e -= 786432;
        if (e < 262144) { cvt8(Yw, Ywb, e); return; }
        e -= 262144;
        if (e < 262144) { cvt8(h2p, A2h, e); return; }
        e -= 262144;
        cvt8(h3p, A3h, e);
        return;
    }

    // ---------------- attn path ----------------
    int n = bb;
    int lane = t & 63, wid = t >> 6;
    const float* cxn = cx + (size_t)n*UU*VV;

    // chunk-0 loads first: fly under abk+phi
    const float* rowp0 = cxn + (size_t)t*VV;
    f32x4u r0[10]; f32x4u rt0;
#pragma unroll
    for (int q = 0; q < 10; ++q) r0[q] = *(const f32x4u*)(rowp0 + q*4);
    rt0 = *(const f32x4u*)(rowp0 + 39);

    // abk: stage x, then wave-parallel dots
    for (int i = t; i < KCAT; i += 256)
        x[i] = (i < HH) ? eh[(size_t)n*HH + i] : wt_1[n*VV + (i - HH)];
    __syncthreads();
#pragma unroll
    for (int rr = 0; rr < 8; ++rr) {
        int g = rr*4 + wid;
        float v = 0.f;
        if (g < 30) {
            const float* w = Ww + (size_t)g*KCAT;
#pragma unroll
            for (int q = 0; q < 9; ++q) {
                int i = q*64 + lane;
                if (i < KCAT) v += x[i]*w[i];
            }
        }
        v += __shfl_xor(v, 32, 64); v += __shfl_xor(v, 16, 64); v += __shfl_xor(v, 8, 64);
        v += __shfl_xor(v, 4, 64);  v += __shfl_xor(v, 2, 64);  v += __shfl_xor(v, 1, 64);
        if (lane == 0 && g < 30) sm[g] = v;
    }
    __syncthreads();
    if (t < 30) {
        float ev = __expf(sm[t] + Wb[t]);
        if (t < 10)       aL[t] = ev + EPSF;
        else if (t < 20)  bL[t-10] = ev + EPSF;
        else { float kap = kappa_prev[n*KMIX + (t-20)] + ev; kL[t-20] = kap;
               kappa_out[n*KMIX + (t-20)] = kap; }
    }
    __syncthreads();
    if (t < KMIX)
        um[t] = kL[t] + sqrtf(fmaxf(60.f + __logf(aL[t]), 0.f) / bL[t]);
    __syncthreads();
    float ulim = um[0];
#pragma unroll
    for (int k = 1; k < KMIX; ++k) ulim = fmaxf(ulim, um[k]);
    int nchunks = min(8, (int)(ulim) / 256 + 1);
    nchunks = __builtin_amdgcn_readfirstlane(nchunks);

    // phi: exact for all u (fast exp)
    float phi_reg[8];
#pragma unroll
    for (int c = 0; c < 8; ++c) {
        int u = c*256 + t; float uu = (float)u, s = 0.f;
#pragma unroll
        for (int k = 0; k < KMIX; ++k) { float d = kL[k] - uu; s += aL[k]*__expf(-bL[k]*d*d); }
        phi_reg[c] = s;
        phi_out[(size_t)n*UU + u] = s;
    }

    // wt: chunk 0 from prefetched regs
    float acc[VV];
    {
        float p = phi_reg[0];
#pragma unroll
        for (int q = 0; q < 10; ++q) {
            acc[q*4+0] = r0[q].x*p; acc[q*4+1] = r0[q].y*p;
            acc[q*4+2] = r0[q].z*p; acc[q*4+3] = r0[q].w*p;
        }
        acc[40] = rt0.y*p; acc[41] = rt0.z*p; acc[42] = rt0.w*p;
    }
#pragma unroll
    for (int c = 1; c < 8; ++c) {
        if (c < nchunks) {
            const float* rowp = cxn + (size_t)(c*256 + t)*VV;
            f32x4u r[10];
#pragma unroll
            for (int q = 0; q < 10; ++q) r[q] = *(const f32x4u*)(rowp + q*4);
            f32x4u rt = *(const f32x4u*)(rowp + 39);
            float p = phi_reg[c];
#pragma unroll
            for (int q = 0; q < 10; ++q) {
                acc[q*4+0] += r[q].x*p; acc[q*4+1] += r[q].y*p;
                acc[q*4+2] += r[q].z*p; acc[q*4+3] += r[q].w*p;
            }
            acc[40] += rt.y*p; acc[41] += rt.z*p; acc[42] += rt.w*p;
        }
    }

    // reduce 256 threads -> wt[43]
#pragma unroll
    for (int v = 0; v < VV; ++v) {
        float val = acc[v];
#pragma unroll
        for (int off = 32; off > 0; off >>= 1) val += __shfl_down(val, off, 64);
        if (lane == 0) red[wid*VV + v] = val;
    }
    __syncthreads();
    if (t < VV) {
        float w4 = red[t] + red[VV+t] + red[2*VV+t] + red[3*VV+t];
        wt_out[n*VV + t] = w4; wtv[t] = w4;
    }
    __syncthreads();
    if (t < 64) {
        float v = (t == 0) ? xt[n] : (t < 44 ? wtv[t-1] : 0.f);
        A2[(size_t)n*64 + t] = f2bf(v);
    }
}

// ---------------------------------------------------------------------------
// Gate-grouped MFMA GEMM + epilogue, v3: m-tile 16, K-interleaved wave pairs.
// Waves: wj = j-half (16 cols), wk = K-step parity. Grid (N/32, M/16) = 512
// blocks -> 2 blocks/CU, 8 waves/CU (2x R6's occupancy). Double-buffered LDS,
// depth-2 register prefetch as in R6. Epilogue: 2-way wk-combine via LDS.
template<int NG, int NSA, int NSB, int EPI>
__global__ __launch_bounds__(256) void gemm_fused(
    const ushortT* __restrict__ Ai, const ushortT* __restrict__ Wi,
    const ushortT* __restrict__ Ah, const ushortT* __restrict__ Wh,
    const float* __restrict__ bih, const float* __restrict__ bhh,
    const float* __restrict__ hprev, const float* __restrict__ resv,
    float* __restrict__ outF, ushortT* __restrict__ outB, const float* __restrict__ Yb)
{
    constexpr int NS = NSA + NSB;
    constexpr int BROWS = NG*32;
    constexpr int STR = (EPI == 0) ? 5 : 17;   // combine stride (padded)
    __shared__ __align__(16) ushortT lA[2][16*64];
    __shared__ __align__(16) ushortT lB[2][BROWS*64];

    int tid = threadIdx.x, lane = tid & 63, wid = tid >> 6;
    int wk = wid >> 1, wj = wid & 1;
    int bj0 = blockIdx.x*32, bm0 = blockIdx.y*16;
    int fcol = lane & 15, g2 = lane >> 4;
    int arow = tid >> 3, aslot = tid & 7;      // A-staging map (tid<128)

    float4 sA[2]; float4 sB[2][NG];

    auto loadregs = [&](int s, int set) {
        const ushortT* Ab; const ushortT* Wsrc; int K, kb;
        if (s < NSA) { Ab = Ai; Wsrc = Wi; K = NSA*64; kb = s*64; }
        else         { Ab = Ah; Wsrc = Wh; K = NSB*64; kb = (s - NSA)*64; }
        if (tid < 128)
            sA[set] = *(const float4*)(Ab + (size_t)(bm0 + arow)*K + kb + aslot*8);
#pragma unroll
        for (int q = 0; q < NG; ++q) {
            int unit = q*256 + tid;
            int brow = unit >> 3, bslot = unit & 7;
            int gate = brow >> 5, r = brow & 31;
            sB[set][q] = *(const float4*)(Wsrc + (size_t)(gate*512 + bj0 + r)*K + kb + bslot*8);
        }
    };
    auto stow = [&](int set, int b) {
        if (tid < 128)
            *(float4*)(&lA[b][arow*64 + (aslot ^ (arow & 7))*8]) = sA[set];
#pragma unroll
        for (int q = 0; q < NG; ++q) {
            int unit = q*256 + tid;
            int brow = unit >> 3, bslot = unit & 7;
            *(float4*)(&lB[b][brow*64 + (bslot ^ (brow & 7))*8]) = sB[set][q];
        }
    };

    f32x4 aR = {0.f,0.f,0.f,0.f}, aZ = {0.f,0.f,0.f,0.f};
    f32x4 aN1 = {0.f,0.f,0.f,0.f}, aN2 = {0.f,0.f,0.f,0.f};

    int ra = fcol;
    int rb = wj*16 + fcol;

    loadregs(0, 0);
    stow(0, 0);
    if (NS > 1) loadregs(1, 1);
    __syncthreads();

#pragma unroll
    for (int s = 0; s < NS; ++s) {
        int cb = s & 1;
        if (s + 2 < NS) loadregs(s + 2, cb);   // set cb's data was stowed at s-1
        bool mine = ((s & 1) == wk);
        bf16x8 af0, af1, b0[NG], b1[NG];
        if (mine) {
            af0 = *(const bf16x8*)(&lA[cb][ra*64 + ((g2    ) ^ (ra & 7))*8]);
            af1 = *(const bf16x8*)(&lA[cb][ra*64 + ((4 + g2) ^ (ra & 7))*8]);
#pragma unroll
            for (int g = 0; g < NG; ++g) {
                int rbt = g*32 + rb;
                b0[g] = *(const bf16x8*)(&lB[cb][rbt*64 + ((g2    ) ^ (rbt & 7))*8]);
                b1[g] = *(const bf16x8*)(&lB[cb][rbt*64 + ((4 + g2) ^ (rbt & 7))*8]);
            }
        }
        if (s + 1 < NS) stow((s + 1) & 1, (s + 1) & 1);
        if (mine) {
            aR = __builtin_amdgcn_mfma_f32_16x16x32_bf16(af0, b0[0], aR, 0, 0, 0);
            aR = __builtin_amdgcn_mfma_f32_16x16x32_bf16(af1, b1[0], aR, 0, 0, 0);
            if constexpr (NG >= 2) {
                aZ = __builtin_amdgcn_mfma_f32_16x16x32_bf16(af0, b0[1], aZ, 0, 0, 0);
                aZ = __builtin_amdgcn_mfma_f32_16x16x32_bf16(af1, b1[1], aZ, 0, 0, 0);
            }
            if constexpr (NG >= 3) {
                if (s < NSA) {
                    aN1 = __builtin_amdgcn_mfma_f32_16x16x32_bf16(af0, b0[2], aN1, 0, 0, 0);
                    aN1 = __builtin_amdgcn_mfma_f32_16x16x32_bf16(af1, b1[2], aN1, 0, 0, 0);
                } else {
                    aN2 = __builtin_amdgcn_mfma_f32_16x16x32_bf16(af0, b0[2], aN2, 0, 0, 0);
                    aN2 = __builtin_amdgcn_mfma_f32_16x16x32_bf16(af1, b1[2], aN2, 0, 0, 0);
                }
            }
        }
        __syncthreads();
    }

    // 2-way wk combine via LDS (loop's final barrier already passed)
    float* cmb = (float*)&lB[0][0];
    if (wk == 1) {
        int base = (wj*64 + lane)*STR;
        *(f32x4*)(cmb + base) = aR;
        if constexpr (EPI != 0) {
            *(f32x4*)(cmb + base + 4)  = aZ;
            *(f32x4*)(cmb + base + 8)  = aN1;
            *(f32x4*)(cmb + base + 12) = aN2;
        }
    }
    __syncthreads();
    if (wk == 0) {
        int base = (wj*64 + lane)*STR;
        aR += *(const f32x4*)(cmb + base);
        if constexpr (EPI != 0) {
            aZ  += *(const f32x4*)(cmb + base + 4);
            aN1 += *(const f32x4*)(cmb + base + 8);
            aN2 += *(const f32x4*)(cmb + base + 12);
        }
        int row0 = bm0 + g2*4;
        int col  = bj0 + wj*16 + fcol;
        if constexpr (EPI == 0) {
            float b = Yb[col];
#pragma unroll
            for (int e = 0; e < 4; ++e)
                outF[(size_t)(row0 + e)*512 + col] = aR[e] + b;
        } else {
            float b_r  = bih[col] + bhh[col];
            float b_z  = bih[512 + col] + bhh[512 + col];
            float b_ni = bih[1024 + col];
            float b_nh = bhh[1024 + col];
#pragma unroll
            for (int e = 0; e < 4; ++e) {
                size_t off = (size_t)(row0 + e)*512 + col;
                float r  = 1.f/(1.f + __expf(-(aR[e] + b_r)));
                float z  = 1.f/(1.f + __expf(-(aZ[e] + b_z)));
                float nn = tanhf(aN1[e] + b_ni + r*(aN2[e] + b_nh));
                float h  = (1.f - z)*nn + z*hprev[off];
                outF[off] = h;
                float xo = (EPI == 2) ? (h + resv[off]) : h;
                outB[off] = f2bf(fmaxf(xo, 0.f));
            }
        }
    }
}

// ---------------------------------------------------------------------------
extern "C" void kernel_launch(void* const* d_in, const int* in_sizes, int n_in,
                              void* d_out, int out_size, void* d_ws, size_t ws_size,
                              hipStream_t stream)
{
    const float* xt   = (const float*)d_in[0];
    const float* cx   = (const float*)d_in[1];
    const float* eh   = (const float*)d_in[2];
    const float* wt_1 = (const float*)d_in[3];
    const float* h2p  = (const float*)d_in[4];
    const float* h3p  = (const float*)d_in[5];
    const float* kp   = (const float*)d_in[6];
    const float* Ww   = (const float*)d_in[7];
    const float* Wb   = (const float*)d_in[8];
    const float* w2ih = (const float*)d_in[9];
    const float* w2hh = (const float*)d_in[10];
    const float* b2ih = (const float*)d_in[11];
    const float* b2hh = (const float*)d_in[12];
    const float* w3ih = (const float*)d_in[13];
    const float* w3hh = (const float*)d_in[14];
    const float* b3ih = (const float*)d_in[15];
    const float* b3hh = (const float*)d_in[16];
    const float* Yw   = (const float*)d_in[17];
    const float* Yb   = (const float*)d_in[18];

    float* out = (float*)d_out;
    float* dist = out + OFF_DIST;
    float* h2o  = out + OFF_H2;
    float* h3o  = out + OFF_H3;
    float* phi  = out + OFF_PHI;
    float* wto  = out + OFF_WT;
    float* kapo = out + OFF_KAPPA;

    char* p = (char*)d_ws;
    ushortT* W2i = (ushortT*)p;  p += (size_t)1536*64*2;
    ushortT* W2h = (ushortT*)p;  p += (size_t)1536*512*2;
    ushortT* W3i = (ushortT*)p;  p += (size_t)1536*512*2;
    ushortT* W3h = (ushortT*)p;  p += (size_t)1536*512*2;
    ushortT* Ywb = (ushortT*)p;  p += (size_t)512*512*2;
    ushortT* A2h = (ushortT*)p;  p += (size_t)512*512*2;
    ushortT* A3h = (ushortT*)p;  p += (size_t)512*512*2;
    ushortT* A2  = (ushortT*)p;  p += (size_t)512*64*2;
    ushortT* A3i = (ushortT*)p;  p += (size_t)512*512*2;
    ushortT* Ad  = (ushortT*)p;  p += (size_t)512*512*2;

    // attn (512 blocks) + pack (1584 blocks, 3244032/8/256) in one launch
    attn_pack<<<512 + 1584, 256, 0, stream>>>(
        xt, cx, eh, wt_1, Ww, Wb, kp, phi, wto, kapo, A2,
        w2ih, w2hh, w3ih, w3hh, Yw, h2p, h3p,
        W2i, W2h, W3i, W3h, Ywb, A2h, A3h);
    // GRU2: gi = [xt|wt] @ w2ih^T (K=64), gh = h2p @ w2hh^T (K=512)
    gemm_fused<3, 1, 8, 1><<<dim3(16, 32), 256, 0, stream>>>(
        A2, W2i, A2h, W2h, b2ih, b2hh, h2p, nullptr, h2o, A3i, nullptr);
    // GRU3: gi = relu(h2) @ w3ih^T, gh = h3p @ w3hh^T
    gemm_fused<3, 8, 8, 2><<<dim3(16, 32), 256, 0, stream>>>(
        A3i, W3i, A3h, W3h, b3ih, b3hh, h3p, h2o, h3o, Ad, nullptr);
    // dist = relu(h3+h2) @ Yw^T + Yb
    gemm_fused<1, 8, 0, 0><<<dim3(16, 32), 256, 0, stream>>>(
        Ad, Ywb, Ad, Ywb, nullptr, nullptr, nullptr, nullptr, dist, nullptr, Yb);
}

// Round 8
// 71.683 us; speedup vs baseline: 1.7511x; 1.7511x over previous
//
#include <hip/hip_runtime.h>
#include <math.h>

typedef unsigned short ushortT;
typedef __attribute__((ext_vector_type(8))) short bf16x8;
typedef __attribute__((ext_vector_type(8))) unsigned short u16x8;
typedef __attribute__((ext_vector_type(4))) float f32x4;
typedef float f32x4u __attribute__((ext_vector_type(4), aligned(4)));

#define NN   512
#define UU   2048
#define VV   43
#define HH   512
#define KMIX 10
#define NCLS 512
#define EPSF 1e-5f
#define KCAT 555     // H + V

// d_out offsets (floats)
#define OFF_DIST  0
#define OFF_H2    262144
#define OFF_H3    524288
#define OFF_PHI   786432
#define OFF_WT    1835008
#define OFF_KAPPA 1857024

__device__ __forceinline__ ushortT f2bf(float f) {
    unsigned int u = __builtin_bit_cast(unsigned int, f);
    u = (u + 0x7fffu + ((u >> 16) & 1u)) >> 16;
    return (ushortT)u;
}

// ---------------------------------------------------------------------------
// Merged attn (blocks 0..511) + pack (blocks 512..2095, x8 vectorized).
__global__ __launch_bounds__(256) void attn_pack(
    const float* __restrict__ xt, const float* __restrict__ cx,
    const float* __restrict__ eh, const float* __restrict__ wt_1,
    const float* __restrict__ Ww, const float* __restrict__ Wb,
    const float* __restrict__ kappa_prev,
    float* __restrict__ phi_out, float* __restrict__ wt_out,
    float* __restrict__ kappa_out, ushortT* __restrict__ A2,
    const float* __restrict__ w2ih, const float* __restrict__ w2hh,
    const float* __restrict__ w3ih, const float* __restrict__ w3hh,
    const float* __restrict__ Yw, const float* __restrict__ h2p,
    const float* __restrict__ h3p,
    ushortT* __restrict__ W2i, ushortT* __restrict__ W2h,
    ushortT* __restrict__ W3i, ushortT* __restrict__ W3h,
    ushortT* __restrict__ Ywb, ushortT* __restrict__ A2h, ushortT* __restrict__ A3h)
{
    __shared__ float x[KCAT];
    __shared__ float sm[32];
    __shared__ float aL[KMIX], bL[KMIX], kL[KMIX], um[KMIX];
    __shared__ float red[4*VV];
    __shared__ float wtv[VV+1];

    int bb = blockIdx.x, t = threadIdx.x;

    if (bb >= NN) {
        // ---------------- pack path: 8 elems per thread ----------------
        int unit = (bb - NN)*256 + t;
        int e = unit*8;
        auto cvt8 = [&](const float* src, ushortT* dst, int off) {
            float4 f0 = *(const float4*)(src + off);
            float4 f1 = *(const float4*)(src + off + 4);
            u16x8 o;
            o[0]=f2bf(f0.x); o[1]=f2bf(f0.y); o[2]=f2bf(f0.z); o[3]=f2bf(f0.w);
            o[4]=f2bf(f1.x); o[5]=f2bf(f1.y); o[6]=f2bf(f1.z); o[7]=f2bf(f1.w);
            *(u16x8*)(dst + off) = o;
        };
        if (e < 98304) {               // W2i: 1536 x 64, cols >=44 zero-padded
            int r = e >> 6, c = e & 63;
            u16x8 o;
#pragma unroll
            for (int i = 0; i < 8; ++i) {
                int cc = c + i;
                o[i] = f2bf(cc < 44 ? w2ih[r*44 + cc] : 0.f);
            }
            *(u16x8*)(W2i + e) = o;
            return;
        }
        e -= 98304;
        if (e < 786432) { cvt8(w2hh, W2h, e); return; }
        e -= 786432;
        if (e < 786432) { cvt8(w3ih, W3i, e); return; }
        e -= 786432;
        if (e < 786432) { cvt8(w3hh, W3h, e); return; }
        e -= 786432;
        if (e < 262144) { cvt8(Yw, Ywb, e); return; }
        e -= 262144;
        if (e < 262144) { cvt8(h2p, A2h, e); return; }
        e -= 262144;
        cvt8(h3p, A3h, e);
        return;
    }

    // ---------------- attn path ----------------
    int n = bb;
    int lane = t & 63, wid = t >> 6;
    const float* cxn = cx + (size_t)n*UU*VV;

    // chunk-0 loads first: fly under abk+phi
    const float* rowp0 = cxn + (size_t)t*VV;
    f32x4u r0[10]; f32x4u rt0;
#pragma unroll
    for (int q = 0; q < 10; ++q) r0[q] = *(const f32x4u*)(rowp0 + q*4);
    rt0 = *(const f32x4u*)(rowp0 + 39);

    // abk: stage x, then wave-parallel dots
    for (int i = t; i < KCAT; i += 256)
        x[i] = (i < HH) ? eh[(size_t)n*HH + i] : wt_1[n*VV + (i - HH)];
    __syncthreads();
#pragma unroll
    for (int rr = 0; rr < 8; ++rr) {
        int g = rr*4 + wid;
        float v = 0.f;
        if (g < 30) {
            const float* w = Ww + (size_t)g*KCAT;
#pragma unroll
            for (int q = 0; q < 9; ++q) {
                int i = q*64 + lane;
                if (i < KCAT) v += x[i]*w[i];
            }
        }
        v += __shfl_xor(v, 32, 64); v += __shfl_xor(v, 16, 64); v += __shfl_xor(v, 8, 64);
        v += __shfl_xor(v, 4, 64);  v += __shfl_xor(v, 2, 64);  v += __shfl_xor(v, 1, 64);
        if (lane == 0 && g < 30) sm[g] = v;
    }
    __syncthreads();
    if (t < 30) {
        float ev = __expf(sm[t] + Wb[t]);
        if (t < 10)       aL[t] = ev + EPSF;
        else if (t < 20)  bL[t-10] = ev + EPSF;
        else { float kap = kappa_prev[n*KMIX + (t-20)] + ev; kL[t-20] = kap;
               kappa_out[n*KMIX + (t-20)] = kap; }
    }
    __syncthreads();
    if (t < KMIX)
        um[t] = kL[t] + sqrtf(fmaxf(60.f + __logf(aL[t]), 0.f) / bL[t]);
    __syncthreads();
    float ulim = um[0];
#pragma unroll
    for (int k = 1; k < KMIX; ++k) ulim = fmaxf(ulim, um[k]);
    int nchunks = min(8, (int)(ulim) / 256 + 1);
    nchunks = __builtin_amdgcn_readfirstlane(nchunks);

    // phi: exact for all u (fast exp)
    float phi_reg[8];
#pragma unroll
    for (int c = 0; c < 8; ++c) {
        int u = c*256 + t; float uu = (float)u, s = 0.f;
#pragma unroll
        for (int k = 0; k < KMIX; ++k) { float d = kL[k] - uu; s += aL[k]*__expf(-bL[k]*d*d); }
        phi_reg[c] = s;
        phi_out[(size_t)n*UU + u] = s;
    }

    // wt: chunk 0 from prefetched regs
    float acc[VV];
    {
        float p = phi_reg[0];
#pragma unroll
        for (int q = 0; q < 10; ++q) {
            acc[q*4+0] = r0[q].x*p; acc[q*4+1] = r0[q].y*p;
            acc[q*4+2] = r0[q].z*p; acc[q*4+3] = r0[q].w*p;
        }
        acc[40] = rt0.y*p; acc[41] = rt0.z*p; acc[42] = rt0.w*p;
    }
#pragma unroll
    for (int c = 1; c < 8; ++c) {
        if (c < nchunks) {
            const float* rowp = cxn + (size_t)(c*256 + t)*VV;
            f32x4u r[10];
#pragma unroll
            for (int q = 0; q < 10; ++q) r[q] = *(const f32x4u*)(rowp + q*4);
            f32x4u rt = *(const f32x4u*)(rowp + 39);
            float p = phi_reg[c];
#pragma unroll
            for (int q = 0; q < 10; ++q) {
                acc[q*4+0] += r[q].x*p; acc[q*4+1] += r[q].y*p;
                acc[q*4+2] += r[q].z*p; acc[q*4+3] += r[q].w*p;
            }
            acc[40] += rt.y*p; acc[41] += rt.z*p; acc[42] += rt.w*p;
        }
    }

    // reduce 256 threads -> wt[43]
#pragma unroll
    for (int v = 0; v < VV; ++v) {
        float val = acc[v];
#pragma unroll
        for (int off = 32; off > 0; off >>= 1) val += __shfl_down(val, off, 64);
        if (lane == 0) red[wid*VV + v] = val;
    }
    __syncthreads();
    if (t < VV) {
        float w4 = red[t] + red[VV+t] + red[2*VV+t] + red[3*VV+t];
        wt_out[n*VV + t] = w4; wtv[t] = w4;
    }
    __syncthreads();
    if (t < 64) {
        float v = (t == 0) ? xt[n] : (t < 44 ? wtv[t-1] : 0.f);
        A2[(size_t)n*64 + t] = f2bf(v);
    }
}

// ---------------------------------------------------------------------------
// Fused gate-grouped MFMA GEMM + epilogue — R6 structure verbatim:
// 32x32 block tile, 4 waves 2x2, LDS double-buffered (one barrier/K-step),
// depth-2 register prefetch.
template<int NG, int NSA, int NSB, int EPI>
__global__ __launch_bounds__(256) void gemm_fused(
    const ushortT* __restrict__ Ai, const ushortT* __restrict__ Wi,
    const ushortT* __restrict__ Ah, const ushortT* __restrict__ Wh,
    const float* __restrict__ bih, const float* __restrict__ bhh,
    const float* __restrict__ hprev, const float* __restrict__ resv,
    float* __restrict__ outF, ushortT* __restrict__ outB, const float* __restrict__ Yb)
{
    constexpr int NS = NSA + NSB;
    __shared__ ushortT lds0[(NG+1)*32*64];
    __shared__ ushortT lds1[(NG+1)*32*64];

    int tid = threadIdx.x, lane = tid & 63, wid = tid >> 6;
    int wm = wid >> 1, wj = wid & 1;
    int bj0 = blockIdx.x*32, bm0 = blockIdx.y*32;
    int fcol = lane & 15, g2 = lane >> 4;

    float4 stgA[NG+1], stgB[NG+1];

    auto loadregs = [&](int s, float4 (&dst)[NG+1]) {
        const ushortT* Ab; const ushortT* Wb_; int K, kb;
        if (s < NSA) { Ab = Ai; Wb_ = Wi; K = NSA*64; kb = s*64; }
        else         { Ab = Ah; Wb_ = Wh; K = NSB*64; kb = (s - NSA)*64; }
        { int row = tid >> 3, slot = tid & 7;
          dst[0] = *(const float4*)(Ab + (size_t)(bm0 + row)*K + kb + slot*8); }
#pragma unroll
        for (int q = 1; q <= NG; ++q) {
            int local = (q-1)*256 + tid;
            int brow = local >> 3, slot = local & 7;
            int gate = brow >> 5, r = brow & 31;
            dst[q] = *(const float4*)(Wb_ + (size_t)(gate*512 + bj0 + r)*K + kb + slot*8);
        }
    };
    auto stow = [&](const float4 (&src)[NG+1], ushortT* buf) {
        { int row = tid >> 3, slot = tid & 7;
          *(float4*)(buf + row*64 + (slot ^ (row & 7))*8) = src[0]; }
#pragma unroll
        for (int q = 1; q <= NG; ++q) {
            int local = (q-1)*256 + tid;
            int brow = local >> 3, slot = local & 7;
            *(float4*)(buf + 2048 + brow*64 + (slot ^ (brow & 7))*8) = src[q];
        }
    };

    f32x4 aR = {0.f,0.f,0.f,0.f}, aZ = {0.f,0.f,0.f,0.f};
    f32x4 aN1 = {0.f,0.f,0.f,0.f}, aN2 = {0.f,0.f,0.f,0.f};

    int ra = wm*16 + fcol, rb = wj*16 + fcol;

    loadregs(0, stgA);
    stow(stgA, lds0);
    loadregs(1, stgB);
    __syncthreads();

#pragma unroll
    for (int s = 0; s < NS; ++s) {
        ushortT* cur = (s & 1) ? lds1 : lds0;
        ushortT* nxt = (s & 1) ? lds0 : lds1;
        if (s + 2 < NS) {
            if (s & 1) loadregs(s + 2, stgB); else loadregs(s + 2, stgA);
        }
        bf16x8 af0 = *(const bf16x8*)(cur + ra*64 + ((g2    ) ^ (ra & 7))*8);
        bf16x8 af1 = *(const bf16x8*)(cur + ra*64 + ((4 + g2) ^ (ra & 7))*8);
        bf16x8 b0[NG], b1[NG];
#pragma unroll
        for (int g = 0; g < NG; ++g) {
            int rbt = g*32 + rb;
            b0[g] = *(const bf16x8*)(cur + 2048 + rbt*64 + ((g2    ) ^ (rbt & 7))*8);
            b1[g] = *(const bf16x8*)(cur + 2048 + rbt*64 + ((4 + g2) ^ (rbt & 7))*8);
        }
        if (s + 1 < NS) {
            if (s & 1) stow(stgA, nxt); else stow(stgB, nxt);
        }
        aR = __builtin_amdgcn_mfma_f32_16x16x32_bf16(af0, b0[0], aR, 0, 0, 0);
        aR = __builtin_amdgcn_mfma_f32_16x16x32_bf16(af1, b1[0], aR, 0, 0, 0);
        if constexpr (NG >= 2) {
            aZ = __builtin_amdgcn_mfma_f32_16x16x32_bf16(af0, b0[1], aZ, 0, 0, 0);
            aZ = __builtin_amdgcn_mfma_f32_16x16x32_bf16(af1, b1[1], aZ, 0, 0, 0);
        }
        if constexpr (NG >= 3) {
            if (s < NSA) {
                aN1 = __builtin_amdgcn_mfma_f32_16x16x32_bf16(af0, b0[2], aN1, 0, 0, 0);
                aN1 = __builtin_amdgcn_mfma_f32_16x16x32_bf16(af1, b1[2], aN1, 0, 0, 0);
            } else {
                aN2 = __builtin_amdgcn_mfma_f32_16x16x32_bf16(af0, b0[2], aN2, 0, 0, 0);
                aN2 = __builtin_amdgcn_mfma_f32_16x16x32_bf16(af1, b1[2], aN2, 0, 0, 0);
            }
        }
        __syncthreads();
    }

    int row0 = bm0 + wm*16 + (lane >> 4)*4;
    int col  = bj0 + wj*16 + fcol;
    if constexpr (EPI == 0) {
        float b = Yb[col];
#pragma unroll
        for (int e = 0; e < 4; ++e)
            outF[(size_t)(row0 + e)*512 + col] = aR[e] + b;
    } else {
        float b_r  = bih[col] + bhh[col];
        float b_z  = bih[512 + col] + bhh[512 + col];
        float b_ni = bih[1024 + col];
        float b_nh = bhh[1024 + col];
#pragma unroll
        for (int e = 0; e < 4; ++e) {
            size_t off = (size_t)(row0 + e)*512 + col;
            float r  = 1.f/(1.f + __expf(-(aR[e] + b_r)));
            float z  = 1.f/(1.f + __expf(-(aZ[e] + b_z)));
            float nn = tanhf(aN1[e] + b_ni + r*(aN2[e] + b_nh));
            float h  = (1.f - z)*nn + z*hprev[off];
            outF[off] = h;
            float xo = (EPI == 2) ? (h + resv[off]) : h;
            outB[off] = f2bf(fmaxf(xo, 0.f));
        }
    }
}

// ---------------------------------------------------------------------------
extern "C" void kernel_launch(void* const* d_in, const int* in_sizes, int n_in,
                              void* d_out, int out_size, void* d_ws, size_t ws_size,
                              hipStream_t stream)
{
    const float* xt   = (const float*)d_in[0];
    const float* cx   = (const float*)d_in[1];
    const float* eh   = (const float*)d_in[2];
    const float* wt_1 = (const float*)d_in[3];
    const float* h2p  = (const float*)d_in[4];
    const float* h3p  = (const float*)d_in[5];
    const float* kp   = (const float*)d_in[6];
    const float* Ww   = (const float*)d_in[7];
    const float* Wb   = (const float*)d_in[8];
    const float* w2ih = (const float*)d_in[9];
    const float* w2hh = (const float*)d_in[10];
    const float* b2ih = (const float*)d_in[11];
    const float* b2hh = (const float*)d_in[12];
    const float* w3ih = (const float*)d_in[13];
    const float* w3hh = (const float*)d_in[14];
    const float* b3ih = (const float*)d_in[15];
    const float* b3hh = (const float*)d_in[16];
    const float* Yw   = (const float*)d_in[17];
    const float* Yb   = (const float*)d_in[18];

    float* out = (float*)d_out;
    float* dist = out + OFF_DIST;
    float* h2o  = out + OFF_H2;
    float* h3o  = out + OFF_H3;
    float* phi  = out + OFF_PHI;
    float* wto  = out + OFF_WT;
    float* kapo = out + OFF_KAPPA;

    char* p = (char*)d_ws;
    ushortT* W2i = (ushortT*)p;  p += (size_t)1536*64*2;
    ushortT* W2h = (ushortT*)p;  p += (size_t)1536*512*2;
    ushortT* W3i = (ushortT*)p;  p += (size_t)1536*512*2;
    ushortT* W3h = (ushortT*)p;  p += (size_t)1536*512*2;
    ushortT* Ywb = (ushortT*)p;  p += (size_t)512*512*2;
    ushortT* A2h = (ushortT*)p;  p += (size_t)512*512*2;
    ushortT* A3h = (ushortT*)p;  p += (size_t)512*512*2;
    ushortT* A2  = (ushortT*)p;  p += (size_t)512*64*2;
    ushortT* A3i = (ushortT*)p;  p += (size_t)512*512*2;
    ushortT* Ad  = (ushortT*)p;  p += (size_t)512*512*2;

    // attn (512 blocks) + pack (1584 blocks) in one launch
    attn_pack<<<512 + 1584, 256, 0, stream>>>(
        xt, cx, eh, wt_1, Ww, Wb, kp, phi, wto, kapo, A2,
        w2ih, w2hh, w3ih, w3hh, Yw, h2p, h3p,
        W2i, W2h, W3i, W3h, Ywb, A2h, A3h);
    // GRU2: gi = [xt|wt] @ w2ih^T (K=64), gh = h2p @ w2hh^T (K=512)
    gemm_fused<3, 1, 8, 1><<<dim3(16, 16), 256, 0, stream>>>(
        A2, W2i, A2h, W2h, b2ih, b2hh, h2p, nullptr, h2o, A3i, nullptr);
    // GRU3: gi = relu(h2) @ w3ih^T, gh = h3p @ w3hh^T
    gemm_fused<3, 8, 8, 2><<<dim3(16, 16), 256, 0, stream>>>(
        A3i, W3i, A3h, W3h, b3ih, b3hh, h3p, h2o, h3o, Ad, nullptr);
    // dist = relu(h3+h2) @ Yw^T + Yb
    gemm_fused<1, 8, 0, 0><<<dim3(16, 16), 256, 0, stream>>>(
        Ad, Ywb, nullptr, nullptr, nullptr, nullptr, nullptr, nullptr, dist, nullptr, Yb);
}